// Round 1
// baseline (1450.156 us; speedup 1.0000x reference)
//
#include <hip/hip_runtime.h>
#include <hip/hip_bf16.h>
#include <stdint.h>

#define B_ 128
#define N_ 512
#define S_ 8
#define H_ 64
#define M_ (B_*N_)          // 65536 rows
#define LSTM_R 16           // rows per LSTM block

__device__ __forceinline__ float sigf(float x)   { return 1.f / (1.f + __expf(-x)); }
__device__ __forceinline__ float tanhf_(float x) { return 1.f - 2.f / (__expf(2.f*x) + 1.f); }
__device__ __forceinline__ float dot4(float4 a, float4 b) {
  return a.x*b.x + a.y*b.y + a.z*b.z + a.w*b.w;
}

// ---------------------------------------------------------------------------
// pad_mask (B,N,N) -> bitmask, 1 bit per (q,key). 134MB -> 4.2MB so the
// attention kernel never does uncoalesced 4B mask reads.
// Works for int32 {0,1} and float32 {0.0,1.0} uploads (bitpattern != 0 test).
__global__ __launch_bounds__(256) void maskpack_kernel(
    const int* __restrict__ pm, uint32_t* __restrict__ bm, int n)
{
  int g = blockIdx.x * 256 + threadIdx.x;
  if (g >= n) return;
  unsigned long long ball = __ballot(pm[g] != 0);
  int lane = threadIdx.x & 63;
  if (lane == 0)       bm[g >> 5] = (uint32_t)ball;
  else if (lane == 32) bm[g >> 5] = (uint32_t)(ball >> 32);
}

// ---------------------------------------------------------------------------
// LSTM over S=8 steps. Gate-parallel: thread j (0..255) owns gate j, Whh row j
// lives in 64 VGPRs. h/c/gates in LDS. 16 rows per block.
__global__ __launch_bounds__(256) void lstm_kernel(
    const float* __restrict__ obs, const float* __restrict__ nhm,
    const float* __restrict__ Wih, const float* __restrict__ Whh,
    const float* __restrict__ bih, const float* __restrict__ bhh,
    float* __restrict__ he)
{
  __shared__ float x_s[LSTM_R][S_][2];
  __shared__ int   len_s[LSTM_R];
  __shared__ float h_s[LSTM_R*64];
  __shared__ float c_s[LSTM_R*64];
  __shared__ float g_s[LSTM_R*256];
  __shared__ float wih_s[512];
  __shared__ float bias_s[256];

  const int tid  = threadIdx.x;
  const int row0 = blockIdx.x * LSTM_R;

  // Whh row tid -> registers (16 float4). Wave-uniform per-lane rows; L2-served.
  float4 w4[16];
  const float4* whh4 = (const float4*)Whh;
  #pragma unroll
  for (int k4 = 0; k4 < 16; ++k4) w4[k4] = whh4[tid*16 + k4];

  bias_s[tid]     = bih[tid] + bhh[tid];
  wih_s[tid]      = Wih[tid];
  wih_s[256+tid]  = Wih[256+tid];
  #pragma unroll
  for (int it = 0; it < 4; ++it) { h_s[it*256+tid] = 0.f; c_s[it*256+tid] = 0.f; }

  // per-row preprocessing: neg_hist_mask mul, last-zero-index (channel 0),
  // kill prefix, length
  if (tid < LSTM_R) {
    int r = tid;
    float xv0[8], xv1[8];
    int lzi = -1;
    for (int t = 0; t < 8; ++t) {
      float m = nhm[(size_t)(row0+r)*8 + t];
      float a = obs[((size_t)(row0+r)*8 + t)*2 + 0] * m;
      float b = obs[((size_t)(row0+r)*8 + t)*2 + 1] * m;
      xv0[t] = a; xv1[t] = b;
      if (a == 0.f) lzi = t;
    }
    for (int t = 0; t < 8; ++t) {
      bool kill = (t < lzi);
      x_s[r][t][0] = kill ? 0.f : xv0[t];
      x_s[r][t][1] = kill ? 0.f : xv1[t];
    }
    int len = 7 - lzi; if (len < 1) len = 1;   // lzi=-1 -> 8
    len_s[r] = len;
  }
  __syncthreads();

  const float wih0 = wih_s[tid*2+0], wih1 = wih_s[tid*2+1], bj = bias_s[tid];

  for (int t = 0; t < 8; ++t) {
    // phase 1: gates for all 16 rows. h reads are wave-broadcast b128.
    for (int r = 0; r < LSTM_R; ++r) {
      float acc = bj + wih0 * x_s[r][t][0] + wih1 * x_s[r][t][1];
      const float4* h4 = (const float4*)(h_s + r*64);
      #pragma unroll
      for (int k4 = 0; k4 < 16; ++k4) {
        float4 hv = h4[k4];
        acc += w4[k4].x*hv.x + w4[k4].y*hv.y + w4[k4].z*hv.z + w4[k4].w*hv.w;
      }
      g_s[r*256 + tid] = acc;   // lane-consecutive, conflict-free
    }
    __syncthreads();
    // phase 2: unit update, 4 (row,unit) items per thread
    #pragma unroll
    for (int it = 0; it < 4; ++it) {
      int idx = it*256 + tid;
      int r = idx >> 6, u = idx & 63;
      if (t < len_s[r]) {
        float gi = g_s[r*256 + u];
        float gf = g_s[r*256 + 64 + u];
        float gg = g_s[r*256 + 128 + u];
        float go = g_s[r*256 + 192 + u];
        float c  = c_s[idx];
        float cn = sigf(gf)*c + sigf(gi)*tanhf_(gg);
        c_s[idx] = cn;
        h_s[idx] = sigf(go)*tanhf_(cn);
      }
    }
    __syncthreads();
  }
  #pragma unroll
  for (int it = 0; it < 4; ++it) {
    int idx = it*256 + tid;
    he[(size_t)row0*64 + idx] = h_s[idx];   // coalesced
  }
}

// ---------------------------------------------------------------------------
// MLP: relu(he) -> 3x relu(64x64) -> hidden -> q,k,v. 32 rows/block.
// Lane = output unit; weights in k4-blocked LDS layout (lane j reads chunk
// k4*64+j -> conflict-free b128); activations broadcast from LDS.
__global__ __launch_bounds__(256) void mlp_kernel(
    const float* __restrict__ he,
    const float* __restrict__ W1, const float* __restrict__ b1,
    const float* __restrict__ W2, const float* __restrict__ b2,
    const float* __restrict__ Wh, const float* __restrict__ bh,
    const float* __restrict__ Wq, const float* __restrict__ bq,
    const float* __restrict__ Wk, const float* __restrict__ bk,
    const float* __restrict__ Wv, const float* __restrict__ bv,
    float* __restrict__ q_out, float* __restrict__ k_out,
    float* __restrict__ feat_out)
{
  __shared__ float4 Wb[3][1024];     // 48 KB (reloaded for q/k/v phase)
  __shared__ float  bias_s[6][64];
  __shared__ float  A[2][32*64];     // 16 KB double buffer

  const int tid  = threadIdx.x;
  const int j    = tid & 63;
  const int rg   = tid >> 6;         // wave id = row group
  const int row0 = blockIdx.x * 32;

  {
    const float* srcA[3] = {W1, W2, Wh};
    for (int m = 0; m < 3; ++m) {
      const float4* s4 = (const float4*)srcA[m];
      #pragma unroll
      for (int n = 0; n < 4; ++n) {
        int i = n*256 + tid;
        Wb[m][(i & 15)*64 + (i >> 4)] = s4[i];
      }
    }
  }
  if (tid < 64) {
    bias_s[0][tid] = b1[tid]; bias_s[1][tid] = b2[tid]; bias_s[2][tid] = bh[tid];
    bias_s[3][tid] = bq[tid]; bias_s[4][tid] = bk[tid]; bias_s[5][tid] = bv[tid];
  }
  #pragma unroll
  for (int n = 0; n < 8; ++n) {
    int i = n*256 + tid;
    A[0][i] = fmaxf(he[(size_t)row0*64 + i], 0.f);   // h1 = relu(he)
  }
  __syncthreads();

  int cur = 0;
  for (int L = 0; L < 3; ++L) {
    float acc[8];
    #pragma unroll
    for (int rr = 0; rr < 8; ++rr) acc[rr] = bias_s[L][j];
    const float4* A4 = (const float4*)A[cur];
    #pragma unroll
    for (int k4 = 0; k4 < 16; ++k4) {
      float4 w = Wb[L][k4*64 + j];
      #pragma unroll
      for (int rr = 0; rr < 8; ++rr) {
        float4 a = A4[(rg*8+rr)*16 + k4];      // wave-broadcast
        acc[rr] += dot4(w, a);
      }
    }
    #pragma unroll
    for (int rr = 0; rr < 8; ++rr)
      A[1-cur][(rg*8+rr)*64 + j] = fmaxf(acc[rr], 0.f);
    __syncthreads();
    cur ^= 1;
  }

  // reload weights for q,k,v (safe: all Wb reads done before last barrier)
  {
    const float* srcB[3] = {Wq, Wk, Wv};
    for (int m = 0; m < 3; ++m) {
      const float4* s4 = (const float4*)srcB[m];
      #pragma unroll
      for (int n = 0; n < 4; ++n) {
        int i = n*256 + tid;
        Wb[m][(i & 15)*64 + (i >> 4)] = s4[i];
      }
    }
  }
  __syncthreads();

  const float4* A4 = (const float4*)A[cur];
  float accq[8], acck[8], accv[8];
  #pragma unroll
  for (int rr = 0; rr < 8; ++rr) {
    accq[rr] = bias_s[3][j]; acck[rr] = bias_s[4][j]; accv[rr] = bias_s[5][j];
  }
  #pragma unroll
  for (int k4 = 0; k4 < 16; ++k4) {
    float4 wq = Wb[0][k4*64+j], wk = Wb[1][k4*64+j], wv = Wb[2][k4*64+j];
    #pragma unroll
    for (int rr = 0; rr < 8; ++rr) {
      float4 a = A4[(rg*8+rr)*16 + k4];
      accq[rr] += dot4(wq, a); acck[rr] += dot4(wk, a); accv[rr] += dot4(wv, a);
    }
  }
  #pragma unroll
  for (int rr = 0; rr < 8; ++rr) {
    int row = row0 + rg*8 + rr;
    q_out[(size_t)row*64 + j]     = accq[rr];   // coalesced
    k_out[(size_t)row*64 + j]     = acck[rr];
    feat_out[(size_t)row*128 + j] = accv[rr];   // v -> feat[:, :64]
  }
}

// ---------------------------------------------------------------------------
// Attention: thread-per-query (256 q/block, 2 blocks/batch). K/V tiles of 128
// keys staged in LDS; exp without max-subtraction (logits << 30 here; masked
// keys get p=0, identical to the -1e12 + softmax reference).
__global__ __launch_bounds__(256) void attn_kernel(
    const float* __restrict__ qg, const float* __restrict__ kg,
    const uint32_t* __restrict__ bm, float* __restrict__ feat)
{
  __shared__ float Kt[128*64];
  __shared__ float Vt[128*64];
  const int tid  = threadIdx.x;
  const int b    = blockIdx.x >> 1;
  const int q0   = (blockIdx.x & 1) << 8;
  const int qrow = b*512 + q0 + tid;

  float4 q4[16];
  const float4* qp = (const float4*)(qg + (size_t)qrow*64);
  #pragma unroll
  for (int i = 0; i < 16; ++i) q4[i] = qp[i];

  float4 o4[16];
  #pragma unroll
  for (int i = 0; i < 16; ++i) o4[i] = make_float4(0.f,0.f,0.f,0.f);
  float l = 0.f;

  for (int kt = 0; kt < 4; ++kt) {
    __syncthreads();
    const float4* Ks = (const float4*)(kg + (size_t)(b*512 + kt*128)*64);
    float4* Kt4 = (float4*)Kt;
    float4* Vt4 = (float4*)Vt;
    const float4* F4 = (const float4*)feat;
    #pragma unroll
    for (int i = 0; i < 8; ++i) {
      int fidx = i*256 + tid;
      Kt4[fidx] = Ks[fidx];
      int vrow = fidx >> 4, c4 = fidx & 15;
      Vt4[fidx] = F4[(size_t)(b*512 + kt*128 + vrow)*32 + c4];
    }
    __syncthreads();

    for (int kw = 0; kw < 4; ++kw) {
      uint32_t w = bm[(size_t)qrow*16 + kt*4 + kw];
      for (int kb = 0; kb < 32; ++kb) {
        int kk = kw*32 + kb;
        const float4* kr = (const float4*)(Kt + kk*64);  // broadcast
        float s = 0.f;
        #pragma unroll
        for (int i = 0; i < 16; ++i) s += dot4(q4[i], kr[i]);
        float p = ((w >> kb) & 1u) ? __expf(fminf(s, 30.f)) : 0.f;
        l += p;
        const float4* vr = (const float4*)(Vt + kk*64);  // broadcast
        #pragma unroll
        for (int i = 0; i < 16; ++i) {
          o4[i].x += p*vr[i].x; o4[i].y += p*vr[i].y;
          o4[i].z += p*vr[i].z; o4[i].w += p*vr[i].w;
        }
      }
    }
  }
  float inv = 1.f / fmaxf(l, 1e-20f);
  float4* op = (float4*)(feat + (size_t)qrow*128 + 64);  // attn -> feat[:,64:]
  #pragma unroll
  for (int i = 0; i < 16; ++i)
    op[i] = make_float4(o4[i].x*inv, o4[i].y*inv, o4[i].z*inv, o4[i].w*inv);
}

// ---------------------------------------------------------------------------
// forecast = feat @ Wf^T + bf   (24 outputs of 128 dims per row)
__global__ __launch_bounds__(256) void forecast_kernel(
    const float* __restrict__ feat, const float* __restrict__ Wf,
    const float* __restrict__ bf, float* __restrict__ out)
{
  __shared__ float4 Wl[768];   // 24 x 32 float4
  __shared__ float  bl[24];
  const int tid = threadIdx.x;
  #pragma unroll
  for (int n = 0; n < 3; ++n) {
    int i = n*256 + tid;
    Wl[i] = ((const float4*)Wf)[i];
  }
  if (tid < 24) bl[tid] = bf[tid];
  __syncthreads();

  int g = blockIdx.x*256 + tid;
  if (g >= M_*24) return;
  int row = g / 24;
  int jj  = g - row*24;
  const float4* f4 = (const float4*)(feat + (size_t)row*128);
  float acc = bl[jj];
  #pragma unroll
  for (int kk = 0; kk < 32; ++kk) {
    int k4 = (kk + jj) & 31;          // rotate start to spread LDS banks
    acc += dot4(Wl[jj*32 + k4], f4[k4]);
  }
  out[g] = acc;
}

// ---------------------------------------------------------------------------
extern "C" void kernel_launch(void* const* d_in, const int* in_sizes, int n_in,
                              void* d_out, int out_size, void* d_ws, size_t ws_size,
                              hipStream_t stream)
{
  const float* obs = (const float*)d_in[0];
  const int*   pm  = (const int*)  d_in[1];
  const float* nhm = (const float*)d_in[2];
  const float* Wih = (const float*)d_in[3];
  const float* Whh = (const float*)d_in[4];
  const float* bih = (const float*)d_in[5];
  const float* bhh = (const float*)d_in[6];
  const float* W1  = (const float*)d_in[7];
  const float* b1  = (const float*)d_in[8];
  const float* W2  = (const float*)d_in[9];
  const float* b2  = (const float*)d_in[10];
  const float* Wh  = (const float*)d_in[11];
  const float* bh  = (const float*)d_in[12];
  const float* Wq  = (const float*)d_in[13];
  const float* bq  = (const float*)d_in[14];
  const float* Wk  = (const float*)d_in[15];
  const float* bk  = (const float*)d_in[16];
  const float* Wv  = (const float*)d_in[17];
  const float* bv  = (const float*)d_in[18];
  const float* Wf  = (const float*)d_in[19];
  const float* bf  = (const float*)d_in[20];

  float* out  = (float*)d_out;                 // forecast: 65536*24
  float* feat = out + (size_t)M_*24;           // feat:     65536*128

  // workspace layout (needs 52 MB): he | q | k | bitmask
  char* ws = (char*)d_ws;
  float*    he  = (float*)(ws);
  float*    qb  = (float*)(ws + (size_t)16*1024*1024);
  float*    kb  = (float*)(ws + (size_t)32*1024*1024);
  uint32_t* bmw = (uint32_t*)(ws + (size_t)48*1024*1024);

  const int nmask = B_*N_*N_;
  maskpack_kernel<<<nmask/256, 256, 0, stream>>>(pm, bmw, nmask);
  lstm_kernel<<<M_/LSTM_R, 256, 0, stream>>>(obs, nhm, Wih, Whh, bih, bhh, he);
  mlp_kernel<<<M_/32, 256, 0, stream>>>(he, W1,b1, W2,b2, Wh,bh, Wq,bq, Wk,bk, Wv,bv,
                                        qb, kb, feat);
  attn_kernel<<<B_*2, 256, 0, stream>>>(qb, kb, bmw, feat);
  forecast_kernel<<<(M_*24 + 255)/256, 256, 0, stream>>>(feat, Wf, bf, out);
}

// Round 2
// 1058.418 us; speedup vs baseline: 1.3701x; 1.3701x over previous
//
#include <hip/hip_runtime.h>
#include <hip/hip_bf16.h>
#include <stdint.h>

#define B_ 128
#define N_ 512
#define S_ 8
#define H_ 64
#define M_ (B_*N_)          // 65536 rows

typedef __attribute__((ext_vector_type(8))) short bf16x8;
typedef __attribute__((ext_vector_type(4))) float f32x4;

__device__ __forceinline__ float sigf(float x)   { return 1.f / (1.f + __expf(-x)); }
__device__ __forceinline__ float tanhf_(float x) { return 1.f - 2.f / (__expf(2.f*x) + 1.f); }
__device__ __forceinline__ float dot4(float4 a, float4 b) {
  return a.x*b.x + a.y*b.y + a.z*b.z + a.w*b.w;
}
// fp32 -> bf16 round-to-nearest-even
__device__ __forceinline__ unsigned short f2bf(float x) {
  unsigned int u = __float_as_uint(x);
  u += 0x7fffu + ((u >> 16) & 1u);
  return (unsigned short)(u >> 16);
}

// ---------------------------------------------------------------------------
// pad_mask (B,N,N) -> bitmask, 1 bit per (q,key).
__global__ __launch_bounds__(256) void maskpack_kernel(
    const int* __restrict__ pm, uint32_t* __restrict__ bm, int n)
{
  int g = blockIdx.x * 256 + threadIdx.x;
  if (g >= n) return;
  unsigned long long ball = __ballot(pm[g] != 0);
  int lane = threadIdx.x & 63;
  if (lane == 0)       bm[g >> 5] = (uint32_t)ball;
  else if (lane == 32) bm[g >> 5] = (uint32_t)(ball >> 32);
}

// ---------------------------------------------------------------------------
// MFMA LSTM. Block = 256 threads = 4 waves; 64 rows/block (16 rows/wave,
// waves independent). Per step, per wave:
//   gates[16][256] = x_t[16][2]@Wih^T + h[16][64]@Whh^T + bias
// via 16 N-tiles x 2 K-halves of mfma_f32_16x16x32_bf16. Whh is converted
// once per block into LDS-resident bf16 B-fragments. h lives in LDS fp32;
// c lives in VGPRs in C-layout. Layouts (verified, learn_hip m89/m120):
//   A: A[m=lane&15][k=quad*8+j]   B: B[k=quad*8+j][n=lane&15]
//   C/D: row=quad*4+reg, col=lane&15
__global__ __launch_bounds__(256) void lstm_kernel(
    const float* __restrict__ obs, const float* __restrict__ nhm,
    const float* __restrict__ Wih, const float* __restrict__ Whh,
    const float* __restrict__ bih, const float* __restrict__ bhh,
    float* __restrict__ he)
{
  __shared__ short Wfrag[32*64*8];     // 32 KB: frag f, lane l -> [f*512 + l*8]
  __shared__ float h_s[64*64];         // 16 KB
  __shared__ float x_s[64][S_][2];     // 4 KB
  __shared__ int   len_s[64];

  const int tid  = threadIdx.x;
  const int lane = tid & 63;
  const int wv   = tid >> 6;           // wave id 0..3
  const int w16  = wv * 16;            // this wave's row offset in block
  const int quad = lane >> 4;
  const int col  = lane & 15;
  const int row0 = blockIdx.x * 64;

  // ---- stage Whh as bf16 B-fragments: entry p = (frag f, lane l) ----
  #pragma unroll
  for (int i = 0; i < 8; ++i) {
    int p = i*256 + tid;
    int f = p >> 6, l = p & 63;
    int t16 = f >> 1, s = f & 1;
    int lq = l >> 4, lc = l & 15;
    const float* src = Whh + (size_t)(t16*16 + lc)*64 + s*32 + lq*8;
    short* dst = Wfrag + f*512 + l*8;
    #pragma unroll
    for (int j = 0; j < 8; ++j) dst[j] = (short)f2bf(src[j]);
  }

  // ---- per-lane constants: bias/Wih for my 16 gate columns ----
  float bias_n[16], wi0[16], wi1[16];
  #pragma unroll
  for (int t16 = 0; t16 < 16; ++t16) {
    int n = t16*16 + col;
    bias_n[t16] = bih[n] + bhh[n];
    wi0[t16] = Wih[2*n + 0];
    wi1[t16] = Wih[2*n + 1];
  }

  // ---- zero h, preprocess x (one row per thread for tid<64) ----
  #pragma unroll
  for (int i = 0; i < 16; ++i) h_s[i*256 + tid] = 0.f;
  if (tid < 64) {
    int r = tid;
    float xv0[8], xv1[8];
    int lzi = -1;
    for (int t = 0; t < 8; ++t) {
      float m = nhm[(size_t)(row0+r)*8 + t];
      float a = obs[((size_t)(row0+r)*8 + t)*2 + 0] * m;
      float b = obs[((size_t)(row0+r)*8 + t)*2 + 1] * m;
      xv0[t] = a; xv1[t] = b;
      if (a == 0.f) lzi = t;
    }
    for (int t = 0; t < 8; ++t) {
      bool kill = (t < lzi);
      x_s[r][t][0] = kill ? 0.f : xv0[t];
      x_s[r][t][1] = kill ? 0.f : xv1[t];
    }
    int len = 7 - lzi; if (len < 1) len = 1;
    len_s[r] = len;
  }
  __syncthreads();

  int lenr[4];
  #pragma unroll
  for (int r = 0; r < 4; ++r) lenr[r] = len_s[w16 + quad*4 + r];

  float c_[16];      // c-state, C-layout: c_[tt*4+r] = c[row=quad*4+r][unit=tt*16+col]
  #pragma unroll
  for (int i = 0; i < 16; ++i) c_[i] = 0.f;

  for (int t = 0; t < 8; ++t) {
    // x for my 4 rows
    float x0[4], x1[4];
    #pragma unroll
    for (int r = 0; r < 4; ++r) {
      x0[r] = x_s[w16 + quad*4 + r][t][0];
      x1[r] = x_s[w16 + quad*4 + r][t][1];
    }

    // init accumulators: bias + x @ Wih^T
    f32x4 acc[16];
    #pragma unroll
    for (int t16 = 0; t16 < 16; ++t16) {
      #pragma unroll
      for (int r = 0; r < 4; ++r)
        acc[t16][r] = bias_n[t16] + wi0[t16]*x0[r] + wi1[t16]*x1[r];
    }

    // A-fragments from h_s (fp32 -> bf16)
    bf16x8 a0, a1;
    {
      const float* hp = &h_s[(w16 + col)*64 + quad*8];
      #pragma unroll
      for (int j = 0; j < 8; ++j) a0[j] = (short)f2bf(hp[j]);
      const float* hq = &h_s[(w16 + col)*64 + 32 + quad*8];
      #pragma unroll
      for (int j = 0; j < 8; ++j) a1[j] = (short)f2bf(hq[j]);
    }

    // 32 MFMAs: gates += h @ Whh^T
    #pragma unroll
    for (int t16 = 0; t16 < 16; ++t16) {
      bf16x8 b0 = *(const bf16x8*)(Wfrag + (t16*2+0)*512 + lane*8);
      bf16x8 b1 = *(const bf16x8*)(Wfrag + (t16*2+1)*512 + lane*8);
      acc[t16] = __builtin_amdgcn_mfma_f32_16x16x32_bf16(a0, b0, acc[t16], 0, 0, 0);
      acc[t16] = __builtin_amdgcn_mfma_f32_16x16x32_bf16(a1, b1, acc[t16], 0, 0, 0);
    }

    // elementwise LSTM cell update (C-layout); units tt*16+col, rows quad*4+r
    #pragma unroll
    for (int tt = 0; tt < 4; ++tt) {
      #pragma unroll
      for (int r = 0; r < 4; ++r) {
        if (t < lenr[r]) {
          float gi = acc[tt   ][r];
          float gf = acc[tt+ 4][r];
          float gg = acc[tt+ 8][r];
          float go = acc[tt+12][r];
          float cn = sigf(gf)*c_[tt*4+r] + sigf(gi)*tanhf_(gg);
          c_[tt*4+r] = cn;
          h_s[(w16 + quad*4 + r)*64 + tt*16 + col] = sigf(go)*tanhf_(cn);
        }
      }
    }
    __syncthreads();
  }

  // ---- write he (coalesced) ----
  #pragma unroll
  for (int i = 0; i < 16; ++i) {
    int idx = i*256 + tid;
    he[(size_t)row0*64 + idx] = h_s[idx];
  }
}

// ---------------------------------------------------------------------------
// MLP: relu(he) -> 3x relu(64x64) -> hidden -> q,k,v. 32 rows/block.
__global__ __launch_bounds__(256) void mlp_kernel(
    const float* __restrict__ he,
    const float* __restrict__ W1, const float* __restrict__ b1,
    const float* __restrict__ W2, const float* __restrict__ b2,
    const float* __restrict__ Wh, const float* __restrict__ bh,
    const float* __restrict__ Wq, const float* __restrict__ bq,
    const float* __restrict__ Wk, const float* __restrict__ bk,
    const float* __restrict__ Wv, const float* __restrict__ bv,
    float* __restrict__ q_out, float* __restrict__ k_out,
    float* __restrict__ feat_out)
{
  __shared__ float4 Wb[3][1024];     // 48 KB (reloaded for q/k/v phase)
  __shared__ float  bias_s[6][64];
  __shared__ float  A[2][32*64];     // 16 KB double buffer

  const int tid  = threadIdx.x;
  const int j    = tid & 63;
  const int rg   = tid >> 6;         // wave id = row group
  const int row0 = blockIdx.x * 32;

  {
    const float* srcA[3] = {W1, W2, Wh};
    for (int m = 0; m < 3; ++m) {
      const float4* s4 = (const float4*)srcA[m];
      #pragma unroll
      for (int n = 0; n < 4; ++n) {
        int i = n*256 + tid;
        Wb[m][(i & 15)*64 + (i >> 4)] = s4[i];
      }
    }
  }
  if (tid < 64) {
    bias_s[0][tid] = b1[tid]; bias_s[1][tid] = b2[tid]; bias_s[2][tid] = bh[tid];
    bias_s[3][tid] = bq[tid]; bias_s[4][tid] = bk[tid]; bias_s[5][tid] = bv[tid];
  }
  #pragma unroll
  for (int n = 0; n < 8; ++n) {
    int i = n*256 + tid;
    A[0][i] = fmaxf(he[(size_t)row0*64 + i], 0.f);   // h1 = relu(he)
  }
  __syncthreads();

  int cur = 0;
  for (int L = 0; L < 3; ++L) {
    float acc[8];
    #pragma unroll
    for (int rr = 0; rr < 8; ++rr) acc[rr] = bias_s[L][j];
    const float4* A4 = (const float4*)A[cur];
    #pragma unroll
    for (int k4 = 0; k4 < 16; ++k4) {
      float4 w = Wb[L][k4*64 + j];
      #pragma unroll
      for (int rr = 0; rr < 8; ++rr) {
        float4 a = A4[(rg*8+rr)*16 + k4];      // wave-broadcast
        acc[rr] += dot4(w, a);
      }
    }
    #pragma unroll
    for (int rr = 0; rr < 8; ++rr)
      A[1-cur][(rg*8+rr)*64 + j] = fmaxf(acc[rr], 0.f);
    __syncthreads();
    cur ^= 1;
  }

  // reload weights for q,k,v (safe: all Wb reads done before last barrier)
  {
    const float* srcB[3] = {Wq, Wk, Wv};
    for (int m = 0; m < 3; ++m) {
      const float4* s4 = (const float4*)srcB[m];
      #pragma unroll
      for (int n = 0; n < 4; ++n) {
        int i = n*256 + tid;
        Wb[m][(i & 15)*64 + (i >> 4)] = s4[i];
      }
    }
  }
  __syncthreads();

  const float4* A4 = (const float4*)A[cur];
  float accq[8], acck[8], accv[8];
  #pragma unroll
  for (int rr = 0; rr < 8; ++rr) {
    accq[rr] = bias_s[3][j]; acck[rr] = bias_s[4][j]; accv[rr] = bias_s[5][j];
  }
  #pragma unroll
  for (int k4 = 0; k4 < 16; ++k4) {
    float4 wq = Wb[0][k4*64+j], wk = Wb[1][k4*64+j], wv = Wb[2][k4*64+j];
    #pragma unroll
    for (int rr = 0; rr < 8; ++rr) {
      float4 a = A4[(rg*8+rr)*16 + k4];
      accq[rr] += dot4(wq, a); acck[rr] += dot4(wk, a); accv[rr] += dot4(wv, a);
    }
  }
  #pragma unroll
  for (int rr = 0; rr < 8; ++rr) {
    int row = row0 + rg*8 + rr;
    q_out[(size_t)row*64 + j]     = accq[rr];   // coalesced
    k_out[(size_t)row*64 + j]     = acck[rr];
    feat_out[(size_t)row*128 + j] = accv[rr];   // v -> feat[:, :64]
  }
}

// ---------------------------------------------------------------------------
// Attention: thread-per-query (256 q/block, 2 blocks/batch).
__global__ __launch_bounds__(256) void attn_kernel(
    const float* __restrict__ qg, const float* __restrict__ kg,
    const uint32_t* __restrict__ bm, float* __restrict__ feat)
{
  __shared__ float Kt[128*64];
  __shared__ float Vt[128*64];
  const int tid  = threadIdx.x;
  const int b    = blockIdx.x >> 1;
  const int q0   = (blockIdx.x & 1) << 8;
  const int qrow = b*512 + q0 + tid;

  float4 q4[16];
  const float4* qp = (const float4*)(qg + (size_t)qrow*64);
  #pragma unroll
  for (int i = 0; i < 16; ++i) q4[i] = qp[i];

  float4 o4[16];
  #pragma unroll
  for (int i = 0; i < 16; ++i) o4[i] = make_float4(0.f,0.f,0.f,0.f);
  float l = 0.f;

  for (int kt = 0; kt < 4; ++kt) {
    __syncthreads();
    const float4* Ks = (const float4*)(kg + (size_t)(b*512 + kt*128)*64);
    float4* Kt4 = (float4*)Kt;
    float4* Vt4 = (float4*)Vt;
    const float4* F4 = (const float4*)feat;
    #pragma unroll
    for (int i = 0; i < 8; ++i) {
      int fidx = i*256 + tid;
      Kt4[fidx] = Ks[fidx];
      int vrow = fidx >> 4, c4 = fidx & 15;
      Vt4[fidx] = F4[(size_t)(b*512 + kt*128 + vrow)*32 + c4];
    }
    __syncthreads();

    for (int kw = 0; kw < 4; ++kw) {
      uint32_t w = bm[(size_t)qrow*16 + kt*4 + kw];
      for (int kb = 0; kb < 32; ++kb) {
        int kk = kw*32 + kb;
        const float4* kr = (const float4*)(Kt + kk*64);  // broadcast
        float s = 0.f;
        #pragma unroll
        for (int i = 0; i < 16; ++i) s += dot4(q4[i], kr[i]);
        float p = ((w >> kb) & 1u) ? __expf(fminf(s, 30.f)) : 0.f;
        l += p;
        const float4* vr = (const float4*)(Vt + kk*64);  // broadcast
        #pragma unroll
        for (int i = 0; i < 16; ++i) {
          o4[i].x += p*vr[i].x; o4[i].y += p*vr[i].y;
          o4[i].z += p*vr[i].z; o4[i].w += p*vr[i].w;
        }
      }
    }
  }
  float inv = 1.f / fmaxf(l, 1e-20f);
  float4* op = (float4*)(feat + (size_t)qrow*128 + 64);  // attn -> feat[:,64:]
  #pragma unroll
  for (int i = 0; i < 16; ++i)
    op[i] = make_float4(o4[i].x*inv, o4[i].y*inv, o4[i].z*inv, o4[i].w*inv);
}

// ---------------------------------------------------------------------------
// forecast = feat @ Wf^T + bf   (24 outputs of 128 dims per row)
__global__ __launch_bounds__(256) void forecast_kernel(
    const float* __restrict__ feat, const float* __restrict__ Wf,
    const float* __restrict__ bf, float* __restrict__ out)
{
  __shared__ float4 Wl[768];   // 24 x 32 float4
  __shared__ float  bl[24];
  const int tid = threadIdx.x;
  #pragma unroll
  for (int n = 0; n < 3; ++n) {
    int i = n*256 + tid;
    Wl[i] = ((const float4*)Wf)[i];
  }
  if (tid < 24) bl[tid] = bf[tid];
  __syncthreads();

  int g = blockIdx.x*256 + tid;
  if (g >= M_*24) return;
  int row = g / 24;
  int jj  = g - row*24;
  const float4* f4 = (const float4*)(feat + (size_t)row*128);
  float acc = bl[jj];
  #pragma unroll
  for (int kk = 0; kk < 32; ++kk) {
    int k4 = (kk + jj) & 31;          // rotate start to spread LDS banks
    acc += dot4(Wl[jj*32 + k4], f4[k4]);
  }
  out[g] = acc;
}

// ---------------------------------------------------------------------------
extern "C" void kernel_launch(void* const* d_in, const int* in_sizes, int n_in,
                              void* d_out, int out_size, void* d_ws, size_t ws_size,
                              hipStream_t stream)
{
  const float* obs = (const float*)d_in[0];
  const int*   pm  = (const int*)  d_in[1];
  const float* nhm = (const float*)d_in[2];
  const float* Wih = (const float*)d_in[3];
  const float* Whh = (const float*)d_in[4];
  const float* bih = (const float*)d_in[5];
  const float* bhh = (const float*)d_in[6];
  const float* W1  = (const float*)d_in[7];
  const float* b1  = (const float*)d_in[8];
  const float* W2  = (const float*)d_in[9];
  const float* b2  = (const float*)d_in[10];
  const float* Wh  = (const float*)d_in[11];
  const float* bh  = (const float*)d_in[12];
  const float* Wq  = (const float*)d_in[13];
  const float* bq  = (const float*)d_in[14];
  const float* Wk  = (const float*)d_in[15];
  const float* bk  = (const float*)d_in[16];
  const float* Wv  = (const float*)d_in[17];
  const float* bv  = (const float*)d_in[18];
  const float* Wf  = (const float*)d_in[19];
  const float* bf  = (const float*)d_in[20];

  float* out  = (float*)d_out;                 // forecast: 65536*24
  float* feat = out + (size_t)M_*24;           // feat:     65536*128

  // workspace layout: he | q | k | bitmask
  char* ws = (char*)d_ws;
  float*    he  = (float*)(ws);
  float*    qb  = (float*)(ws + (size_t)16*1024*1024);
  float*    kb  = (float*)(ws + (size_t)32*1024*1024);
  uint32_t* bmw = (uint32_t*)(ws + (size_t)48*1024*1024);

  const int nmask = B_*N_*N_;
  maskpack_kernel<<<nmask/256, 256, 0, stream>>>(pm, bmw, nmask);
  lstm_kernel<<<M_/64, 256, 0, stream>>>(obs, nhm, Wih, Whh, bih, bhh, he);
  mlp_kernel<<<M_/32, 256, 0, stream>>>(he, W1,b1, W2,b2, Wh,bh, Wq,bq, Wk,bk, Wv,bv,
                                        qb, kb, feat);
  attn_kernel<<<B_*2, 256, 0, stream>>>(qb, kb, bmw, feat);
  forecast_kernel<<<(M_*24 + 255)/256, 256, 0, stream>>>(feat, Wf, bf, out);
}

// Round 3
// 575.970 us; speedup vs baseline: 2.5178x; 1.8376x over previous
//
#include <hip/hip_runtime.h>
#include <hip/hip_bf16.h>
#include <stdint.h>

#define B_ 128
#define N_ 512
#define S_ 8
#define H_ 64
#define M_ (B_*N_)          // 65536 rows

typedef __attribute__((ext_vector_type(8))) short bf16x8;
typedef __attribute__((ext_vector_type(4))) float f32x4;

__device__ __forceinline__ float sigf(float x)   { return 1.f / (1.f + __expf(-x)); }
__device__ __forceinline__ float tanhf_(float x) { return 1.f - 2.f / (__expf(2.f*x) + 1.f); }
__device__ __forceinline__ float dot4(float4 a, float4 b) {
  return a.x*b.x + a.y*b.y + a.z*b.z + a.w*b.w;
}
// fp32 -> bf16 round-to-nearest-even
__device__ __forceinline__ unsigned short f2bf(float x) {
  unsigned int u = __float_as_uint(x);
  u += 0x7fffu + ((u >> 16) & 1u);
  return (unsigned short)(u >> 16);
}

// ---------------------------------------------------------------------------
// pad_mask (B,N,N) -> bitmask, 1 bit per (q,key).
__global__ __launch_bounds__(256) void maskpack_kernel(
    const int* __restrict__ pm, uint32_t* __restrict__ bm, int n)
{
  int g = blockIdx.x * 256 + threadIdx.x;
  if (g >= n) return;
  unsigned long long ball = __ballot(pm[g] != 0);
  int lane = threadIdx.x & 63;
  if (lane == 0)       bm[g >> 5] = (uint32_t)ball;
  else if (lane == 32) bm[g >> 5] = (uint32_t)(ball >> 32);
}

// ---------------------------------------------------------------------------
// MFMA LSTM (unchanged from R1; verified). 64 rows/block, 16 rows/wave.
__global__ __launch_bounds__(256) void lstm_kernel(
    const float* __restrict__ obs, const float* __restrict__ nhm,
    const float* __restrict__ Wih, const float* __restrict__ Whh,
    const float* __restrict__ bih, const float* __restrict__ bhh,
    float* __restrict__ he)
{
  __shared__ short Wfrag[32*64*8];     // 32 KB
  __shared__ float h_s[64*64];         // 16 KB
  __shared__ float x_s[64][S_][2];
  __shared__ int   len_s[64];

  const int tid  = threadIdx.x;
  const int lane = tid & 63;
  const int wv   = tid >> 6;
  const int w16  = wv * 16;
  const int quad = lane >> 4;
  const int col  = lane & 15;
  const int row0 = blockIdx.x * 64;

  #pragma unroll
  for (int i = 0; i < 8; ++i) {
    int p = i*256 + tid;
    int f = p >> 6, l = p & 63;
    int t16 = f >> 1, s = f & 1;
    int lq = l >> 4, lc = l & 15;
    const float* src = Whh + (size_t)(t16*16 + lc)*64 + s*32 + lq*8;
    short* dst = Wfrag + f*512 + l*8;
    #pragma unroll
    for (int j = 0; j < 8; ++j) dst[j] = (short)f2bf(src[j]);
  }

  float bias_n[16], wi0[16], wi1[16];
  #pragma unroll
  for (int t16 = 0; t16 < 16; ++t16) {
    int n = t16*16 + col;
    bias_n[t16] = bih[n] + bhh[n];
    wi0[t16] = Wih[2*n + 0];
    wi1[t16] = Wih[2*n + 1];
  }

  #pragma unroll
  for (int i = 0; i < 16; ++i) h_s[i*256 + tid] = 0.f;
  if (tid < 64) {
    int r = tid;
    float xv0[8], xv1[8];
    int lzi = -1;
    for (int t = 0; t < 8; ++t) {
      float m = nhm[(size_t)(row0+r)*8 + t];
      float a = obs[((size_t)(row0+r)*8 + t)*2 + 0] * m;
      float b = obs[((size_t)(row0+r)*8 + t)*2 + 1] * m;
      xv0[t] = a; xv1[t] = b;
      if (a == 0.f) lzi = t;
    }
    for (int t = 0; t < 8; ++t) {
      bool kill = (t < lzi);
      x_s[r][t][0] = kill ? 0.f : xv0[t];
      x_s[r][t][1] = kill ? 0.f : xv1[t];
    }
    int len = 7 - lzi; if (len < 1) len = 1;
    len_s[r] = len;
  }
  __syncthreads();

  int lenr[4];
  #pragma unroll
  for (int r = 0; r < 4; ++r) lenr[r] = len_s[w16 + quad*4 + r];

  float c_[16];
  #pragma unroll
  for (int i = 0; i < 16; ++i) c_[i] = 0.f;

  for (int t = 0; t < 8; ++t) {
    float x0[4], x1[4];
    #pragma unroll
    for (int r = 0; r < 4; ++r) {
      x0[r] = x_s[w16 + quad*4 + r][t][0];
      x1[r] = x_s[w16 + quad*4 + r][t][1];
    }

    f32x4 acc[16];
    #pragma unroll
    for (int t16 = 0; t16 < 16; ++t16) {
      #pragma unroll
      for (int r = 0; r < 4; ++r)
        acc[t16][r] = bias_n[t16] + wi0[t16]*x0[r] + wi1[t16]*x1[r];
    }

    bf16x8 a0, a1;
    {
      const float* hp = &h_s[(w16 + col)*64 + quad*8];
      #pragma unroll
      for (int j = 0; j < 8; ++j) a0[j] = (short)f2bf(hp[j]);
      const float* hq = &h_s[(w16 + col)*64 + 32 + quad*8];
      #pragma unroll
      for (int j = 0; j < 8; ++j) a1[j] = (short)f2bf(hq[j]);
    }

    #pragma unroll
    for (int t16 = 0; t16 < 16; ++t16) {
      bf16x8 b0 = *(const bf16x8*)(Wfrag + (t16*2+0)*512 + lane*8);
      bf16x8 b1 = *(const bf16x8*)(Wfrag + (t16*2+1)*512 + lane*8);
      acc[t16] = __builtin_amdgcn_mfma_f32_16x16x32_bf16(a0, b0, acc[t16], 0, 0, 0);
      acc[t16] = __builtin_amdgcn_mfma_f32_16x16x32_bf16(a1, b1, acc[t16], 0, 0, 0);
    }

    #pragma unroll
    for (int tt = 0; tt < 4; ++tt) {
      #pragma unroll
      for (int r = 0; r < 4; ++r) {
        if (t < lenr[r]) {
          float gi = acc[tt   ][r];
          float gf = acc[tt+ 4][r];
          float gg = acc[tt+ 8][r];
          float go = acc[tt+12][r];
          float cn = sigf(gf)*c_[tt*4+r] + sigf(gi)*tanhf_(gg);
          c_[tt*4+r] = cn;
          h_s[(w16 + quad*4 + r)*64 + tt*16 + col] = sigf(go)*tanhf_(cn);
        }
      }
    }
    __syncthreads();
  }

  #pragma unroll
  for (int i = 0; i < 16; ++i) {
    int idx = i*256 + tid;
    he[(size_t)row0*64 + idx] = h_s[idx];
  }
}

// ---------------------------------------------------------------------------
// MLP (unchanged from R1)
__global__ __launch_bounds__(256) void mlp_kernel(
    const float* __restrict__ he,
    const float* __restrict__ W1, const float* __restrict__ b1,
    const float* __restrict__ W2, const float* __restrict__ b2,
    const float* __restrict__ Wh, const float* __restrict__ bh,
    const float* __restrict__ Wq, const float* __restrict__ bq,
    const float* __restrict__ Wk, const float* __restrict__ bk,
    const float* __restrict__ Wv, const float* __restrict__ bv,
    float* __restrict__ q_out, float* __restrict__ k_out,
    float* __restrict__ feat_out)
{
  __shared__ float4 Wb[3][1024];
  __shared__ float  bias_s[6][64];
  __shared__ float  A[2][32*64];

  const int tid  = threadIdx.x;
  const int j    = tid & 63;
  const int rg   = tid >> 6;
  const int row0 = blockIdx.x * 32;

  {
    const float* srcA[3] = {W1, W2, Wh};
    for (int m = 0; m < 3; ++m) {
      const float4* s4 = (const float4*)srcA[m];
      #pragma unroll
      for (int n = 0; n < 4; ++n) {
        int i = n*256 + tid;
        Wb[m][(i & 15)*64 + (i >> 4)] = s4[i];
      }
    }
  }
  if (tid < 64) {
    bias_s[0][tid] = b1[tid]; bias_s[1][tid] = b2[tid]; bias_s[2][tid] = bh[tid];
    bias_s[3][tid] = bq[tid]; bias_s[4][tid] = bk[tid]; bias_s[5][tid] = bv[tid];
  }
  #pragma unroll
  for (int n = 0; n < 8; ++n) {
    int i = n*256 + tid;
    A[0][i] = fmaxf(he[(size_t)row0*64 + i], 0.f);
  }
  __syncthreads();

  int cur = 0;
  for (int L = 0; L < 3; ++L) {
    float acc[8];
    #pragma unroll
    for (int rr = 0; rr < 8; ++rr) acc[rr] = bias_s[L][j];
    const float4* A4 = (const float4*)A[cur];
    #pragma unroll
    for (int k4 = 0; k4 < 16; ++k4) {
      float4 w = Wb[L][k4*64 + j];
      #pragma unroll
      for (int rr = 0; rr < 8; ++rr) {
        float4 a = A4[(rg*8+rr)*16 + k4];
        acc[rr] += dot4(w, a);
      }
    }
    #pragma unroll
    for (int rr = 0; rr < 8; ++rr)
      A[1-cur][(rg*8+rr)*64 + j] = fmaxf(acc[rr], 0.f);
    __syncthreads();
    cur ^= 1;
  }

  {
    const float* srcB[3] = {Wq, Wk, Wv};
    for (int m = 0; m < 3; ++m) {
      const float4* s4 = (const float4*)srcB[m];
      #pragma unroll
      for (int n = 0; n < 4; ++n) {
        int i = n*256 + tid;
        Wb[m][(i & 15)*64 + (i >> 4)] = s4[i];
      }
    }
  }
  __syncthreads();

  const float4* A4 = (const float4*)A[cur];
  float accq[8], acck[8], accv[8];
  #pragma unroll
  for (int rr = 0; rr < 8; ++rr) {
    accq[rr] = bias_s[3][j]; acck[rr] = bias_s[4][j]; accv[rr] = bias_s[5][j];
  }
  #pragma unroll
  for (int k4 = 0; k4 < 16; ++k4) {
    float4 wq = Wb[0][k4*64+j], wk = Wb[1][k4*64+j], wv = Wb[2][k4*64+j];
    #pragma unroll
    for (int rr = 0; rr < 8; ++rr) {
      float4 a = A4[(rg*8+rr)*16 + k4];
      accq[rr] += dot4(wq, a); acck[rr] += dot4(wk, a); accv[rr] += dot4(wv, a);
    }
  }
  #pragma unroll
  for (int rr = 0; rr < 8; ++rr) {
    int row = row0 + rg*8 + rr;
    q_out[(size_t)row*64 + j]     = accq[rr];
    k_out[(size_t)row*64 + j]     = acck[rr];
    feat_out[(size_t)row*128 + j] = accv[rr];
  }
}

// ---------------------------------------------------------------------------
// MFMA attention. Block = 4 waves = 64 queries (16 q/wave); grid = M/64.
// Key chunks of 128 staged in LDS (K bf16 [key][dim] stride 72; V^T bf16
// [dim][key] stride 136 -> dense bank patterns for b128 fragment reads).
// QK^T: 2 MFMAs per 16-key tile (Q A-frags in regs). exp/mask in fp32 on
// C-layout. P relayout C->A through per-wave swizzled LDS tile (m120
// pattern). PV: 4 MFMAs per k32. No max-subtraction (logits ~O(0.3));
// masked keys get p=0 exactly.
__global__ __launch_bounds__(256) void attn_kernel(
    const float* __restrict__ qg, const float* __restrict__ kg,
    const uint32_t* __restrict__ bm, float* __restrict__ feat)
{
  __shared__ short    Ks[128*72];      // 18.0 KB
  __shared__ short    Vt[64*136];      // 17.0 KB
  __shared__ short    Pl[4][16*32];    // 4 KB, per-wave
  __shared__ uint32_t Ms[4][256];      // 4 KB, per-wave mask words

  const int tid  = threadIdx.x;
  const int lane = tid & 63;
  const int wv   = tid >> 6;
  const int quad = lane >> 4;
  const int col  = lane & 15;

  const int b     = blockIdx.x >> 3;
  const int q0    = (blockIdx.x & 7) * 64;
  const int qbase = b*512 + q0 + wv*16;     // global row of this wave's q-tile

  // Q A-fragments: A[m=col][k=quad*8+j], two k32 halves
  bf16x8 qa[2];
  {
    const float* qp = qg + (size_t)(qbase + col)*64 + quad*8;
    #pragma unroll
    for (int s = 0; s < 2; ++s) {
      float4 f0 = *(const float4*)(qp + s*32);
      float4 f1 = *(const float4*)(qp + s*32 + 4);
      qa[s][0]=(short)f2bf(f0.x); qa[s][1]=(short)f2bf(f0.y);
      qa[s][2]=(short)f2bf(f0.z); qa[s][3]=(short)f2bf(f0.w);
      qa[s][4]=(short)f2bf(f1.x); qa[s][5]=(short)f2bf(f1.y);
      qa[s][6]=(short)f2bf(f1.z); qa[s][7]=(short)f2bf(f1.w);
    }
  }

  // mask words for my wave's 16 q rows (contiguous, coalesced)
  #pragma unroll
  for (int w = 0; w < 4; ++w)
    Ms[wv][w*64 + lane] = bm[(size_t)qbase*16 + w*64 + lane];

  f32x4 o_acc[4];
  #pragma unroll
  for (int nt = 0; nt < 4; ++nt)
    #pragma unroll
    for (int r = 0; r < 4; ++r) o_acc[nt][r] = 0.f;
  float l_part[4] = {0.f, 0.f, 0.f, 0.f};

  for (int c = 0; c < 4; ++c) {
    __syncthreads();    // all waves done reading previous chunk
    // ---- stage K chunk: bf16 [key][dim], stride 72 ----
    {
      const int kb = b*512 + c*128;
      #pragma unroll
      for (int i = 0; i < 8; ++i) {
        int p = i*256 + tid;
        int key = p >> 4, d4 = p & 15;
        float4 v = *(const float4*)(kg + (size_t)(kb + key)*64 + d4*4);
        short* dst = Ks + key*72 + d4*4;
        dst[0]=(short)f2bf(v.x); dst[1]=(short)f2bf(v.y);
        dst[2]=(short)f2bf(v.z); dst[3]=(short)f2bf(v.w);
      }
      // ---- stage V^T chunk: bf16 [dim][key], stride 136 ----
      #pragma unroll
      for (int i = 0; i < 8; ++i) {
        int p = i*256 + tid;
        int vrow = p >> 4, c4 = p & 15;
        float4 v = *(const float4*)(feat + (size_t)(kb + vrow)*128 + c4*4);
        Vt[(c4*4+0)*136 + vrow] = (short)f2bf(v.x);
        Vt[(c4*4+1)*136 + vrow] = (short)f2bf(v.y);
        Vt[(c4*4+2)*136 + vrow] = (short)f2bf(v.z);
        Vt[(c4*4+3)*136 + vrow] = (short)f2bf(v.w);
      }
    }
    __syncthreads();

    for (int kc = 0; kc < 4; ++kc) {          // k32 chunks within key-chunk
      #pragma unroll
      for (int t = 0; t < 2; ++t) {           // two 16-key tiles
        const int kt = kc*2 + t;
        f32x4 s_acc;
        #pragma unroll
        for (int r = 0; r < 4; ++r) s_acc[r] = 0.f;
        const short* kp = Ks + (kt*16 + col)*72 + quad*8;
        bf16x8 kb0 = *(const bf16x8*)(kp);
        bf16x8 kb1 = *(const bf16x8*)(kp + 32);
        s_acc = __builtin_amdgcn_mfma_f32_16x16x32_bf16(qa[0], kb0, s_acc, 0,0,0);
        s_acc = __builtin_amdgcn_mfma_f32_16x16x32_bf16(qa[1], kb1, s_acc, 0,0,0);
        // mask + exp + store P (bf16, quad-swizzled columns)
        const int kcol = ((t*16 + col) ^ (quad*8));
        #pragma unroll
        for (int r = 0; r < 4; ++r) {
          uint32_t mw = Ms[wv][(quad*4+r)*16 + c*4 + (kt>>1)];
          float p = ((mw >> ((kt&1)*16 + col)) & 1u)
                      ? __expf(fminf(s_acc[r], 30.f)) : 0.f;
          l_part[r] += p;
          Pl[wv][(quad*4+r)*32 + kcol] = (short)f2bf(p);
        }
      }
      // A-frag of P (same wave wrote it; compiler inserts lgkmcnt wait)
      bf16x8 pa = *(const bf16x8*)(&Pl[wv][col*32 + ((quad*8) ^ (((col)>>2)*8))]);
      #pragma unroll
      for (int nt = 0; nt < 4; ++nt) {
        bf16x8 vb = *(const bf16x8*)(&Vt[(nt*16+col)*136 + kc*32 + quad*8]);
        o_acc[nt] = __builtin_amdgcn_mfma_f32_16x16x32_bf16(pa, vb, o_acc[nt], 0,0,0);
      }
    }
  }

  // reduce l across the 16 cols (lanes sharing a quad)
  float inv[4];
  #pragma unroll
  for (int r = 0; r < 4; ++r) {
    float v = l_part[r];
    v += __shfl_xor(v, 1);
    v += __shfl_xor(v, 2);
    v += __shfl_xor(v, 4);
    v += __shfl_xor(v, 8);
    inv[r] = 1.f / fmaxf(v, 1e-20f);
  }

  // write attn -> feat[:, 64:] (C-layout: row=quad*4+r, col=nt*16+col)
  #pragma unroll
  for (int nt = 0; nt < 4; ++nt)
    #pragma unroll
    for (int r = 0; r < 4; ++r)
      feat[(size_t)(qbase + quad*4 + r)*128 + 64 + nt*16 + col] = o_acc[nt][r]*inv[r];
}

// ---------------------------------------------------------------------------
// forecast = feat @ Wf^T + bf
__global__ __launch_bounds__(256) void forecast_kernel(
    const float* __restrict__ feat, const float* __restrict__ Wf,
    const float* __restrict__ bf, float* __restrict__ out)
{
  __shared__ float4 Wl[768];
  __shared__ float  bl[24];
  const int tid = threadIdx.x;
  #pragma unroll
  for (int n = 0; n < 3; ++n) {
    int i = n*256 + tid;
    Wl[i] = ((const float4*)Wf)[i];
  }
  if (tid < 24) bl[tid] = bf[tid];
  __syncthreads();

  int g = blockIdx.x*256 + tid;
  if (g >= M_*24) return;
  int row = g / 24;
  int jj  = g - row*24;
  const float4* f4 = (const float4*)(feat + (size_t)row*128);
  float acc = bl[jj];
  #pragma unroll
  for (int kk = 0; kk < 32; ++kk) {
    int k4 = (kk + jj) & 31;
    acc += dot4(Wl[jj*32 + k4], f4[k4]);
  }
  out[g] = acc;
}

// ---------------------------------------------------------------------------
extern "C" void kernel_launch(void* const* d_in, const int* in_sizes, int n_in,
                              void* d_out, int out_size, void* d_ws, size_t ws_size,
                              hipStream_t stream)
{
  const float* obs = (const float*)d_in[0];
  const int*   pm  = (const int*)  d_in[1];
  const float* nhm = (const float*)d_in[2];
  const float* Wih = (const float*)d_in[3];
  const float* Whh = (const float*)d_in[4];
  const float* bih = (const float*)d_in[5];
  const float* bhh = (const float*)d_in[6];
  const float* W1  = (const float*)d_in[7];
  const float* b1  = (const float*)d_in[8];
  const float* W2  = (const float*)d_in[9];
  const float* b2  = (const float*)d_in[10];
  const float* Wh  = (const float*)d_in[11];
  const float* bh  = (const float*)d_in[12];
  const float* Wq  = (const float*)d_in[13];
  const float* bq  = (const float*)d_in[14];
  const float* Wk  = (const float*)d_in[15];
  const float* bk  = (const float*)d_in[16];
  const float* Wv  = (const float*)d_in[17];
  const float* bv  = (const float*)d_in[18];
  const float* Wf  = (const float*)d_in[19];
  const float* bf  = (const float*)d_in[20];

  float* out  = (float*)d_out;                 // forecast: 65536*24
  float* feat = out + (size_t)M_*24;           // feat:     65536*128

  char* ws = (char*)d_ws;
  float*    he  = (float*)(ws);
  float*    qb  = (float*)(ws + (size_t)16*1024*1024);
  float*    kb  = (float*)(ws + (size_t)32*1024*1024);
  uint32_t* bmw = (uint32_t*)(ws + (size_t)48*1024*1024);

  const int nmask = B_*N_*N_;
  maskpack_kernel<<<nmask/256, 256, 0, stream>>>(pm, bmw, nmask);
  lstm_kernel<<<M_/64, 256, 0, stream>>>(obs, nhm, Wih, Whh, bih, bhh, he);
  mlp_kernel<<<M_/32, 256, 0, stream>>>(he, W1,b1, W2,b2, Wh,bh, Wq,bq, Wk,bk, Wv,bv,
                                        qb, kb, feat);
  attn_kernel<<<M_/64, 256, 0, stream>>>(qb, kb, bmw, feat);
  forecast_kernel<<<(M_*24 + 255)/256, 256, 0, stream>>>(feat, Wf, bf, out);
}

// Round 4
// 476.331 us; speedup vs baseline: 3.0444x; 1.2092x over previous
//
#include <hip/hip_runtime.h>
#include <hip/hip_bf16.h>
#include <stdint.h>

#define B_ 128
#define N_ 512
#define S_ 8
#define H_ 64
#define M_ (B_*N_)          // 65536 rows
#define L2E 1.442695041f

typedef __attribute__((ext_vector_type(8))) short bf16x8;
typedef __attribute__((ext_vector_type(4))) float f32x4;

__device__ __forceinline__ float exp2f_(float x) { return __builtin_amdgcn_exp2f(x); }
// x pre-scaled by log2(e):  sig2(x) == sigmoid(x / L2E)
__device__ __forceinline__ float sig2(float x)  { return 1.f / (1.f + exp2f_(-x)); }
// x pre-scaled by 2*log2(e): tanh2(x) == tanh(x / (2*L2E))
__device__ __forceinline__ float tanh2(float x) { return 1.f - 2.f / (exp2f_(x) + 1.f); }
__device__ __forceinline__ float dot4(float4 a, float4 b) {
  return a.x*b.x + a.y*b.y + a.z*b.z + a.w*b.w;
}
// fp32 -> bf16 round-to-nearest-even
__device__ __forceinline__ unsigned short f2bf(float x) {
  unsigned int u = __float_as_uint(x);
  u += 0x7fffu + ((u >> 16) & 1u);
  return (unsigned short)(u >> 16);
}

// ---------------------------------------------------------------------------
// pad_mask (B,N,N) -> bitmask, 1 bit per (q,key).
__global__ __launch_bounds__(256) void maskpack_kernel(
    const int* __restrict__ pm, uint32_t* __restrict__ bm, int n)
{
  int g = blockIdx.x * 256 + threadIdx.x;
  if (g >= n) return;
  unsigned long long ball = __ballot(pm[g] != 0);
  int lane = threadIdx.x & 63;
  if (lane == 0)       bm[g >> 5] = (uint32_t)ball;
  else if (lane == 32) bm[g >> 5] = (uint32_t)(ball >> 32);
}

// ---------------------------------------------------------------------------
// MFMA LSTM. 64 rows/block, 16 rows/wave. Changes vs R2:
//  - h_s stride 64 -> 68 floats (A-frag read + h-write now conflict-free)
//  - log2e folded into Whh/Wih/bias at staging (i,f,o: *L2E; g: *2*L2E)
//    so gate nonlinearities use raw v_exp2 (saves 4 v_mul/cell)
//  - he output stored as relu'd bf16 (mlp consumes it as MFMA A-fragments)
__global__ __launch_bounds__(256) void lstm_kernel(
    const float* __restrict__ obs, const float* __restrict__ nhm,
    const float* __restrict__ Wih, const float* __restrict__ Whh,
    const float* __restrict__ bih, const float* __restrict__ bhh,
    unsigned short* __restrict__ he)
{
  __shared__ short Wfrag[32*64*8];     // 32 KB
  __shared__ float h_s[64*68];         // 17.4 KB (stride 68: conflict-free)
  __shared__ float x_s[64][18];        // 4.6 KB ([t*2+ch], padded stride)
  __shared__ int   len_s[64];

  const int tid  = threadIdx.x;
  const int lane = tid & 63;
  const int wv   = tid >> 6;
  const int w16  = wv * 16;
  const int quad = lane >> 4;
  const int col  = lane & 15;
  const int row0 = blockIdx.x * 64;

  // stage Whh as bf16 B-fragments, pre-scaled per gate type
  #pragma unroll
  for (int i = 0; i < 8; ++i) {
    int p = i*256 + tid;
    int f = p >> 6, l = p & 63;
    int t16 = f >> 1, s = f & 1;
    int lq = l >> 4, lc = l & 15;
    const float sc = (t16 >= 8 && t16 < 12) ? (2.f*L2E) : L2E;
    const float* src = Whh + (size_t)(t16*16 + lc)*64 + s*32 + lq*8;
    short* dst = Wfrag + f*512 + l*8;
    #pragma unroll
    for (int j = 0; j < 8; ++j) dst[j] = (short)f2bf(src[j] * sc);
  }

  float bias_n[16], wi0[16], wi1[16];
  #pragma unroll
  for (int t16 = 0; t16 < 16; ++t16) {
    int n = t16*16 + col;
    const float sc = (t16 >= 8 && t16 < 12) ? (2.f*L2E) : L2E;
    bias_n[t16] = (bih[n] + bhh[n]) * sc;
    wi0[t16] = Wih[2*n + 0] * sc;
    wi1[t16] = Wih[2*n + 1] * sc;
  }

  #pragma unroll
  for (int i = 0; i < 17; ++i) h_s[i*256 + tid] = 0.f;
  if (tid < 64) {
    int r = tid;
    float xv0[8], xv1[8];
    int lzi = -1;
    for (int t = 0; t < 8; ++t) {
      float m = nhm[(size_t)(row0+r)*8 + t];
      float a = obs[((size_t)(row0+r)*8 + t)*2 + 0] * m;
      float b = obs[((size_t)(row0+r)*8 + t)*2 + 1] * m;
      xv0[t] = a; xv1[t] = b;
      if (a == 0.f) lzi = t;
    }
    for (int t = 0; t < 8; ++t) {
      bool kill = (t < lzi);
      x_s[r][t*2+0] = kill ? 0.f : xv0[t];
      x_s[r][t*2+1] = kill ? 0.f : xv1[t];
    }
    int len = 7 - lzi; if (len < 1) len = 1;
    len_s[r] = len;
  }
  __syncthreads();

  int lenr[4];
  #pragma unroll
  for (int r = 0; r < 4; ++r) lenr[r] = len_s[w16 + quad*4 + r];

  float c_[16];
  #pragma unroll
  for (int i = 0; i < 16; ++i) c_[i] = 0.f;

  for (int t = 0; t < 8; ++t) {
    float x0[4], x1[4];
    #pragma unroll
    for (int r = 0; r < 4; ++r) {
      x0[r] = x_s[w16 + quad*4 + r][t*2+0];
      x1[r] = x_s[w16 + quad*4 + r][t*2+1];
    }

    f32x4 acc[16];
    #pragma unroll
    for (int t16 = 0; t16 < 16; ++t16) {
      #pragma unroll
      for (int r = 0; r < 4; ++r)
        acc[t16][r] = bias_n[t16] + wi0[t16]*x0[r] + wi1[t16]*x1[r];
    }

    bf16x8 a0, a1;
    {
      const float* hp = &h_s[(w16 + col)*68 + quad*8];
      #pragma unroll
      for (int j = 0; j < 8; ++j) a0[j] = (short)f2bf(hp[j]);
      const float* hq = &h_s[(w16 + col)*68 + 32 + quad*8];
      #pragma unroll
      for (int j = 0; j < 8; ++j) a1[j] = (short)f2bf(hq[j]);
    }

    #pragma unroll
    for (int t16 = 0; t16 < 16; ++t16) {
      bf16x8 b0 = *(const bf16x8*)(Wfrag + (t16*2+0)*512 + lane*8);
      bf16x8 b1 = *(const bf16x8*)(Wfrag + (t16*2+1)*512 + lane*8);
      acc[t16] = __builtin_amdgcn_mfma_f32_16x16x32_bf16(a0, b0, acc[t16], 0, 0, 0);
      acc[t16] = __builtin_amdgcn_mfma_f32_16x16x32_bf16(a1, b1, acc[t16], 0, 0, 0);
    }

    #pragma unroll
    for (int tt = 0; tt < 4; ++tt) {
      #pragma unroll
      for (int r = 0; r < 4; ++r) {
        if (t < lenr[r]) {
          float gi = acc[tt   ][r];
          float gf = acc[tt+ 4][r];
          float gg = acc[tt+ 8][r];
          float go = acc[tt+12][r];
          float cn = sig2(gf)*c_[tt*4+r] + sig2(gi)*tanh2(gg);
          c_[tt*4+r] = cn;
          h_s[(w16 + quad*4 + r)*68 + tt*16 + col] = sig2(go)*tanh2(cn*(2.f*L2E));
        }
      }
    }
    __syncthreads();
  }

  // write he = relu(h) as bf16, row-major, coalesced packed-pair stores
  #pragma unroll
  for (int i = 0; i < 8; ++i) {
    int p = i*256 + tid;               // pair index (2048 pairs)
    int row = p >> 5, u2 = (p & 31)*2;
    float v0 = fmaxf(h_s[row*68 + u2    ], 0.f);
    float v1 = fmaxf(h_s[row*68 + u2 + 1], 0.f);
    uint32_t pk = (uint32_t)f2bf(v0) | ((uint32_t)f2bf(v1) << 16);
    *(uint32_t*)(he + (size_t)(row0+row)*64 + u2) = pk;
  }
}

// ---------------------------------------------------------------------------
// MFMA MLP: 3x relu(64x64) -> hidden -> q,k,v. 64 rows/block, 16 rows/wave.
// A-frags chained layer-to-layer via per-wave swizzled bf16 tile (stride 76,
// k ^ (r*16) swizzle). Weights as LDS B-frags, restaged once for q/k/v.
// q,k emitted bf16 (attn input); v relayouted to coalesced fp32 feat stores.
__global__ __launch_bounds__(256) void mlp_kernel(
    const unsigned short* __restrict__ he,
    const float* __restrict__ W1, const float* __restrict__ b1,
    const float* __restrict__ W2, const float* __restrict__ b2,
    const float* __restrict__ Wh, const float* __restrict__ bh,
    const float* __restrict__ Wq, const float* __restrict__ bq,
    const float* __restrict__ Wk, const float* __restrict__ bk,
    const float* __restrict__ Wv, const float* __restrict__ bv,
    unsigned short* __restrict__ qb, unsigned short* __restrict__ kb,
    float* __restrict__ feat)
{
  __shared__ short Wm[3][8*512];       // 24 KB B-frags (3 matrices at a time)
  __shared__ float bias_s[6*64];       // 1.5 KB
  __shared__ short Atile[4][16*76];    // 9.5 KB per-wave bf16 relayout tiles
  __shared__ float Otile[4][16*68];    // 17 KB per-wave fp32 out tiles

  const int tid  = threadIdx.x;
  const int lane = tid & 63;
  const int wv   = tid >> 6;
  const int quad = lane >> 4;
  const int col  = lane & 15;
  const int rowb = blockIdx.x*64 + wv*16;

  // ---- stage 3 weight matrices as B-frags ----
  const float* m1[3] = {W1, W2, Wh};
  const float* m2[3] = {Wq, Wk, Wv};
  auto stage3 = [&](const float* const* mats) {
    #pragma unroll
    for (int i = 0; i < 6; ++i) {
      int p = i*256 + tid;             // 1536 (matrix,frag,lane) entries
      int m = p >> 9, rem = p & 511;
      int f = rem >> 6, l = rem & 63;
      int nt = f >> 1, s = f & 1;
      int lq = l >> 4, lc = l & 15;
      const float* src = mats[m] + (size_t)(nt*16 + lc)*64 + s*32 + lq*8;
      short* dst = &Wm[m][f*512 + l*8];
      #pragma unroll
      for (int j = 0; j < 8; ++j) dst[j] = (short)f2bf(src[j]);
    }
  };
  stage3(m1);
  {
    const float* bs[6] = {b1, b2, bh, bq, bk, bv};
    for (int i = tid; i < 384; i += 256) bias_s[i] = bs[i>>6][i & 63];
  }
  __syncthreads();

  // ---- initial A-frags straight from global he (already relu'd bf16) ----
  bf16x8 a0 = *(const bf16x8*)(he + (size_t)(rowb + col)*64 + quad*8);
  bf16x8 a1 = *(const bf16x8*)(he + (size_t)(rowb + col)*64 + quad*8 + 32);

  f32x4 acc[4];
  auto runL = [&](int m, int bidx) {
    #pragma unroll
    for (int nt = 0; nt < 4; ++nt) {
      float bb = bias_s[bidx*64 + nt*16 + col];
      acc[nt][0] = bb; acc[nt][1] = bb; acc[nt][2] = bb; acc[nt][3] = bb;
    }
    #pragma unroll
    for (int nt = 0; nt < 4; ++nt) {
      bf16x8 bf0 = *(const bf16x8*)(&Wm[m][(nt*2+0)*512 + lane*8]);
      bf16x8 bf1 = *(const bf16x8*)(&Wm[m][(nt*2+1)*512 + lane*8]);
      acc[nt] = __builtin_amdgcn_mfma_f32_16x16x32_bf16(a0, bf0, acc[nt], 0,0,0);
      acc[nt] = __builtin_amdgcn_mfma_f32_16x16x32_bf16(a1, bf1, acc[nt], 0,0,0);
    }
  };
  auto tileWrite = [&](bool relu) {
    #pragma unroll
    for (int nt = 0; nt < 4; ++nt)
      #pragma unroll
      for (int r = 0; r < 4; ++r) {
        float v = relu ? fmaxf(acc[nt][r], 0.f) : acc[nt][r];
        Atile[wv][(quad*4+r)*76 + ((nt*16+col) ^ (r*16))] = (short)f2bf(v);
      }
  };
  auto tileReadA = [&]() {            // same-wave RAW: DS pipe is in-order
    int sw = (col & 3) * 16;
    a0 = *(const bf16x8*)(&Atile[wv][col*76 + ((quad*8     ) ^ sw)]);
    a1 = *(const bf16x8*)(&Atile[wv][col*76 + ((quad*8 + 32) ^ sw)]);
  };
  auto storeBF = [&](unsigned short* dst) {
    #pragma unroll
    for (int s = 0; s < 2; ++s) {
      int chunk = s*64 + lane;
      int r = chunk >> 3, c8 = chunk & 7;
      bf16x8 v = *(const bf16x8*)(&Atile[wv][r*76 + ((c8*8) ^ ((r&3)*16))]);
      *(bf16x8*)(dst + (size_t)(rowb + r)*64 + c8*8) = v;
    }
  };

  runL(0, 0); tileWrite(true); tileReadA();
  runL(1, 1); tileWrite(true); tileReadA();
  runL(2, 2); tileWrite(true); tileReadA();      // a0/a1 = hidden A-frags
  __syncthreads();                                // all waves done with W1-3
  stage3(m2);
  __syncthreads();

  runL(0, 3); tileWrite(false); storeBF(qb);      // q (bf16)
  runL(1, 4); tileWrite(false); storeBF(kb);      // k (bf16)
  runL(2, 5);                                     // v -> feat[:, :64] fp32
  #pragma unroll
  for (int nt = 0; nt < 4; ++nt)
    #pragma unroll
    for (int r = 0; r < 4; ++r)
      Otile[wv][(quad*4+r)*68 + nt*16 + col] = acc[nt][r];
  #pragma unroll
  for (int i = 0; i < 4; ++i) {
    int idx = i*64 + lane;
    int r = idx >> 4, c4 = idx & 15;
    float4 v = *(const float4*)(&Otile[wv][r*68 + c4*4]);
    *(float4*)(feat + (size_t)(rowb + r)*128 + c4*4) = v;
  }
}

// ---------------------------------------------------------------------------
// MFMA attention (R2 structure; q/k now bf16 inputs — no staging converts).
__global__ __launch_bounds__(256) void attn_kernel(
    const unsigned short* __restrict__ qg, const unsigned short* __restrict__ kg,
    const uint32_t* __restrict__ bm, float* __restrict__ feat)
{
  __shared__ short    Ks[128*72];      // 18.0 KB
  __shared__ short    Vt[64*136];      // 17.0 KB
  __shared__ short    Pl[4][16*32];    // 4 KB, per-wave
  __shared__ uint32_t Ms[4][256];      // 4 KB, per-wave mask words

  const int tid  = threadIdx.x;
  const int lane = tid & 63;
  const int wv   = tid >> 6;
  const int quad = lane >> 4;
  const int col  = lane & 15;

  const int b     = blockIdx.x >> 3;
  const int q0    = (blockIdx.x & 7) * 64;
  const int qbase = b*512 + q0 + wv*16;

  bf16x8 qa[2];
  qa[0] = *(const bf16x8*)(qg + (size_t)(qbase + col)*64 + quad*8);
  qa[1] = *(const bf16x8*)(qg + (size_t)(qbase + col)*64 + quad*8 + 32);

  #pragma unroll
  for (int w = 0; w < 4; ++w)
    Ms[wv][w*64 + lane] = bm[(size_t)qbase*16 + w*64 + lane];

  f32x4 o_acc[4];
  #pragma unroll
  for (int nt = 0; nt < 4; ++nt)
    #pragma unroll
    for (int r = 0; r < 4; ++r) o_acc[nt][r] = 0.f;
  float l_part[4] = {0.f, 0.f, 0.f, 0.f};

  for (int c = 0; c < 4; ++c) {
    __syncthreads();
    {
      const int kb_ = b*512 + c*128;
      // K chunk: bf16 [key][dim] stride 72 — direct b128 copies
      #pragma unroll
      for (int i = 0; i < 4; ++i) {
        int p = i*256 + tid;
        int key = p >> 3, c8 = p & 7;
        bf16x8 kv = *(const bf16x8*)(kg + (size_t)(kb_ + key)*64 + c8*8);
        *(bf16x8*)(Ks + key*72 + c8*8) = kv;
      }
      // V^T chunk: fp32 feat -> bf16 [dim][key] stride 136
      #pragma unroll
      for (int i = 0; i < 8; ++i) {
        int p = i*256 + tid;
        int vrow = p >> 4, c4 = p & 15;
        float4 v = *(const float4*)(feat + (size_t)(kb_ + vrow)*128 + c4*4);
        Vt[(c4*4+0)*136 + vrow] = (short)f2bf(v.x);
        Vt[(c4*4+1)*136 + vrow] = (short)f2bf(v.y);
        Vt[(c4*4+2)*136 + vrow] = (short)f2bf(v.z);
        Vt[(c4*4+3)*136 + vrow] = (short)f2bf(v.w);
      }
    }
    __syncthreads();

    for (int kc = 0; kc < 4; ++kc) {
      #pragma unroll
      for (int t = 0; t < 2; ++t) {
        const int kt = kc*2 + t;
        f32x4 s_acc;
        #pragma unroll
        for (int r = 0; r < 4; ++r) s_acc[r] = 0.f;
        const short* kp = Ks + (kt*16 + col)*72 + quad*8;
        bf16x8 kb0 = *(const bf16x8*)(kp);
        bf16x8 kb1 = *(const bf16x8*)(kp + 32);
        s_acc = __builtin_amdgcn_mfma_f32_16x16x32_bf16(qa[0], kb0, s_acc, 0,0,0);
        s_acc = __builtin_amdgcn_mfma_f32_16x16x32_bf16(qa[1], kb1, s_acc, 0,0,0);
        const int kcol = ((t*16 + col) ^ (quad*8));
        #pragma unroll
        for (int r = 0; r < 4; ++r) {
          uint32_t mw = Ms[wv][(quad*4+r)*16 + c*4 + (kt>>1)];
          float p = ((mw >> ((kt&1)*16 + col)) & 1u)
                      ? exp2f_(fminf(s_acc[r], 30.f) * L2E) : 0.f;
          l_part[r] += p;
          Pl[wv][(quad*4+r)*32 + kcol] = (short)f2bf(p);
        }
      }
      bf16x8 pa = *(const bf16x8*)(&Pl[wv][col*32 + ((quad*8) ^ (((col)>>2)*8))]);
      #pragma unroll
      for (int nt = 0; nt < 4; ++nt) {
        bf16x8 vb = *(const bf16x8*)(&Vt[(nt*16+col)*136 + kc*32 + quad*8]);
        o_acc[nt] = __builtin_amdgcn_mfma_f32_16x16x32_bf16(pa, vb, o_acc[nt], 0,0,0);
      }
    }
  }

  float inv[4];
  #pragma unroll
  for (int r = 0; r < 4; ++r) {
    float v = l_part[r];
    v += __shfl_xor(v, 1);
    v += __shfl_xor(v, 2);
    v += __shfl_xor(v, 4);
    v += __shfl_xor(v, 8);
    inv[r] = 1.f / fmaxf(v, 1e-20f);
  }

  #pragma unroll
  for (int nt = 0; nt < 4; ++nt)
    #pragma unroll
    for (int r = 0; r < 4; ++r)
      feat[(size_t)(qbase + quad*4 + r)*128 + 64 + nt*16 + col] = o_acc[nt][r]*inv[r];
}

// ---------------------------------------------------------------------------
// forecast = feat @ Wf^T + bf
__global__ __launch_bounds__(256) void forecast_kernel(
    const float* __restrict__ feat, const float* __restrict__ Wf,
    const float* __restrict__ bf, float* __restrict__ out)
{
  __shared__ float4 Wl[768];
  __shared__ float  bl[24];
  const int tid = threadIdx.x;
  #pragma unroll
  for (int n = 0; n < 3; ++n) {
    int i = n*256 + tid;
    Wl[i] = ((const float4*)Wf)[i];
  }
  if (tid < 24) bl[tid] = bf[tid];
  __syncthreads();

  int g = blockIdx.x*256 + tid;
  if (g >= M_*24) return;
  int row = g / 24;
  int jj  = g - row*24;
  const float4* f4 = (const float4*)(feat + (size_t)row*128);
  float acc = bl[jj];
  #pragma unroll
  for (int kk = 0; kk < 32; ++kk) {
    int k4 = (kk + jj) & 31;
    acc += dot4(Wl[jj*32 + k4], f4[k4]);
  }
  out[g] = acc;
}

// ---------------------------------------------------------------------------
extern "C" void kernel_launch(void* const* d_in, const int* in_sizes, int n_in,
                              void* d_out, int out_size, void* d_ws, size_t ws_size,
                              hipStream_t stream)
{
  const float* obs = (const float*)d_in[0];
  const int*   pm  = (const int*)  d_in[1];
  const float* nhm = (const float*)d_in[2];
  const float* Wih = (const float*)d_in[3];
  const float* Whh = (const float*)d_in[4];
  const float* bih = (const float*)d_in[5];
  const float* bhh = (const float*)d_in[6];
  const float* W1  = (const float*)d_in[7];
  const float* b1  = (const float*)d_in[8];
  const float* W2  = (const float*)d_in[9];
  const float* b2  = (const float*)d_in[10];
  const float* Wh  = (const float*)d_in[11];
  const float* bh  = (const float*)d_in[12];
  const float* Wq  = (const float*)d_in[13];
  const float* bq  = (const float*)d_in[14];
  const float* Wk  = (const float*)d_in[15];
  const float* bk  = (const float*)d_in[16];
  const float* Wv  = (const float*)d_in[17];
  const float* bv  = (const float*)d_in[18];
  const float* Wf  = (const float*)d_in[19];
  const float* bf  = (const float*)d_in[20];

  float* out  = (float*)d_out;                 // forecast: 65536*24
  float* feat = out + (size_t)M_*24;           // feat:     65536*128

  // workspace: he(bf16 8MB) | qb(bf16 8MB) | kb(bf16 8MB) | bitmask(4.2MB)
  char* ws = (char*)d_ws;
  unsigned short* he  = (unsigned short*)(ws);
  unsigned short* qbf = (unsigned short*)(ws + (size_t)16*1024*1024);
  unsigned short* kbf = (unsigned short*)(ws + (size_t)32*1024*1024);
  uint32_t*       bmw = (uint32_t*)      (ws + (size_t)48*1024*1024);

  const int nmask = B_*N_*N_;
  maskpack_kernel<<<nmask/256, 256, 0, stream>>>(pm, bmw, nmask);
  lstm_kernel<<<M_/64, 256, 0, stream>>>(obs, nhm, Wih, Whh, bih, bhh, he);
  mlp_kernel<<<M_/64, 256, 0, stream>>>(he, W1,b1, W2,b2, Wh,bh, Wq,bq, Wk,bk, Wv,bv,
                                        qbf, kbf, feat);
  attn_kernel<<<M_/64, 256, 0, stream>>>(qbf, kbf, bmw, feat);
  forecast_kernel<<<(M_*24 + 255)/256, 256, 0, stream>>>(feat, Wf, bf, out);
}